// Round 5
// baseline (303.775 us; speedup 1.0000x reference)
//
#include <hip/hip_runtime.h>
#include <cstdint>

typedef uint16_t u16;
typedef __attribute__((ext_vector_type(8))) short bf16x8;
typedef __attribute__((ext_vector_type(4))) short bf16x4;
typedef __attribute__((ext_vector_type(4))) float f32x4;

// 0.125 * log2(e): folded into Q projection so softmax is exp2(s) directly.
#define QSCALE 0.18033688011112042f

struct Ptr3 { const float* a; const float* b; const float* c; };

__device__ __forceinline__ u16 f2bf(float x) {
  union { float f; uint32_t u; } v; v.f = x;
  uint32_t r = (v.u + 0x7fffu + ((v.u >> 16) & 1u)) >> 16;
  return (u16)r;
}

__device__ __forceinline__ bf16x8 cvt8(f32x4 lo, f32x4 hi) {
  bf16x8 o;
  o[0] = (short)f2bf(lo[0]); o[1] = (short)f2bf(lo[1]);
  o[2] = (short)f2bf(lo[2]); o[3] = (short)f2bf(lo[3]);
  o[4] = (short)f2bf(hi[0]); o[5] = (short)f2bf(hi[1]);
  o[6] = (short)f2bf(hi[2]); o[7] = (short)f2bf(hi[3]);
  return o;
}

// ---------------- fused Wq/Wk/Wv transpose: grid (16,1,48) ----------------
// W[h][d][k] (f32, 1024x64 per head) -> wt[w][h*64+k][d] (bf16)
// tile stride 65 u16 (odd) -> conflict-free scalar transpose.
__global__ __launch_bounds__(256) void k_transpose_w(Ptr3 w, u16* __restrict__ out) {
  __shared__ u16 tile[64 * 65];
  const int t = threadIdx.x;
  const int z = blockIdx.z;
  const float* in = (z < 16) ? w.a : (z < 32 ? w.b : w.c);
  const long in_base = (long)(z & 15) * 65536;
  const long out_base = (long)z * 65536;
  const int r0 = blockIdx.x * 64;
  for (int e = t; e < 4096; e += 256) {
    int rr = e >> 6, cc = e & 63;
    tile[rr * 65 + cc] = f2bf(in[in_base + (long)(r0 + rr) * 64 + cc]);
  }
  __syncthreads();
  for (int s = t; s < 512; s += 256) {
    int cc = s >> 3, r8 = (s & 7) << 3;
    bf16x8 p;
    #pragma unroll
    for (int j = 0; j < 8; ++j) p[j] = (short)tile[(r8 + j) * 65 + cc];
    *(bf16x8*)(out + out_base + (long)cc * 1024 + r0 + r8) = p;
  }
}

// ---------------- generic tiled transpose -> bf16 ----------------
__global__ __launch_bounds__(256) void k_transpose_bf16(const void* __restrict__ in,
                                                        int in_is_f32, u16* __restrict__ out,
                                                        int rstride, int R, int sph,
                                                        long slab_lo, long slab_hi) {
  __shared__ u16 tile[64 * 65];
  const int t = threadIdx.x;
  const long z = blockIdx.z;
  const long in_base = (z / sph) * slab_hi + (z % sph) * slab_lo;
  const long out_base = z * (long)R * (long)(gridDim.y * 64);
  const int r0 = blockIdx.x * 64, c0 = blockIdx.y * 64;
  for (int e = t; e < 4096; e += 256) {
    int rr = e >> 6, cc = e & 63;
    long src = in_base + (long)(r0 + rr) * rstride + c0 + cc;
    u16 w = in_is_f32 ? f2bf(((const float*)in)[src]) : ((const u16*)in)[src];
    tile[rr * 65 + cc] = w;
  }
  __syncthreads();
  for (int s = t; s < 512; s += 256) {
    int cc = s >> 3, r8 = (s & 7) << 3;
    bf16x8 p;
    #pragma unroll
    for (int j = 0; j < 8; ++j) p[j] = (short)tile[(r8 + j) * 65 + cc];
    *(bf16x8*)(out + out_base + (long)(c0 + cc) * R + r0 + r8) = p;
  }
}

// ---- fused cast+QKV GEMM: 128x128 tile, grid (8,32,3), reg-prefetch staging
// A f32 (query/key/value), Bt bf16 (NxK). C bf16 = (A*Bt^T)*scale.
// LDS stride 34 u16 (17 dwords, odd) -> <=2-way banks on all reads/writes.
__global__ __launch_bounds__(256, 3) void k_gemm_qkv(Ptr3 Af, const u16* __restrict__ B0,
                                                     u16* __restrict__ C0, float scale0) {
  __shared__ __align__(16) u16 As[128 * 34];
  __shared__ __align__(16) u16 Bs[128 * 34];
  const int z = blockIdx.z;
  const float* A = z == 0 ? Af.a : (z == 1 ? Af.b : Af.c);
  const u16* Bt = B0 + (long)z * 1048576;
  u16* C = C0 + (long)z * 4194304;
  const float scale = z ? 1.0f : scale0;
  const int t = threadIdx.x, lane = t & 63, quad = lane >> 4, l16 = lane & 15;
  const int wave = t >> 6, wy = wave >> 1, wx = wave & 1;
  const int m0 = blockIdx.y * 128, n0 = blockIdx.x * 128;
  // staging map: row = t>>1 (0..127), half = t&1 (16 elems each)
  const int srow = t >> 1, shalf = t & 1;
  const float* aptr = A + (long)(m0 + srow) * 1024 + shalf * 16;
  const u16* bptr = Bt + (long)(n0 + srow) * 1024 + shalf * 16;
  u16* asl = As + srow * 34 + shalf * 16;
  u16* bsl = Bs + srow * 34 + shalf * 16;

  f32x4 ar[4];
  bf16x8 br[2];
  auto loadT = [&](int k0) {
    #pragma unroll
    for (int i = 0; i < 4; ++i) ar[i] = ((const f32x4*)(aptr + k0))[i];
    br[0] = ((const bf16x8*)(bptr + k0))[0];
    br[1] = ((const bf16x8*)(bptr + k0))[1];
  };
  auto writeT = [&]() {
    *(bf16x8*)asl = cvt8(ar[0], ar[1]);
    *(bf16x8*)(asl + 8) = cvt8(ar[2], ar[3]);
    *(bf16x8*)bsl = br[0];
    *(bf16x8*)(bsl + 8) = br[1];
  };

  loadT(0);
  writeT();
  __syncthreads();

  f32x4 acc[4][4] = {};
  for (int k0 = 0; k0 < 1024; k0 += 32) {
    const bool pre = (k0 + 32) < 1024;
    if (pre) loadT(k0 + 32);   // in flight across the MFMA phase
    bf16x8 af[4], bfr[4];
    #pragma unroll
    for (int mt = 0; mt < 4; ++mt)
      af[mt] = *(const bf16x8*)(As + (wy * 64 + mt * 16 + l16) * 34 + quad * 8);
    #pragma unroll
    for (int nt = 0; nt < 4; ++nt)
      bfr[nt] = *(const bf16x8*)(Bs + (wx * 64 + nt * 16 + l16) * 34 + quad * 8);
    #pragma unroll
    for (int mt = 0; mt < 4; ++mt)
      #pragma unroll
      for (int nt = 0; nt < 4; ++nt)
        acc[mt][nt] = __builtin_amdgcn_mfma_f32_16x16x32_bf16(af[mt], bfr[nt], acc[mt][nt], 0, 0, 0);
    __syncthreads();
    if (pre) writeT();
    __syncthreads();
  }
  #pragma unroll
  for (int mt = 0; mt < 4; ++mt)
    #pragma unroll
    for (int nt = 0; nt < 4; ++nt) {
      int col = n0 + wx * 64 + nt * 16 + l16;
      #pragma unroll
      for (int r = 0; r < 4; ++r) {
        int row = m0 + wy * 64 + mt * 16 + quad * 4 + r;
        C[(long)row * 1024 + col] = f2bf(acc[mt][nt][r] * scale);
      }
    }
}

// ---- out-proj GEMM: 128x64 tile, grid (16,32), reg-prefetch staging, f32+bias
__global__ __launch_bounds__(256, 2) void k_gemm_out(const u16* __restrict__ A,
                                                     const u16* __restrict__ Bt,
                                                     float* __restrict__ C,
                                                     const float* __restrict__ bias) {
  __shared__ __align__(16) u16 As[128 * 34];
  __shared__ __align__(16) u16 Bs[64 * 34];
  const int t = threadIdx.x, lane = t & 63, quad = lane >> 4, l16 = lane & 15;
  const int wave = t >> 6;
  const int m0 = blockIdx.y * 128, n0 = blockIdx.x * 64;
  // A staging: 512 slots (row 0..127 x chunk 0..3), 2 per thread
  const int ar0 = t >> 2, ac0 = t & 3;        // slot t
  const int ar1 = (t + 256) >> 2, ac1 = t & 3; // slot t+256
  const int brow = t >> 2, bc = t & 3;         // B: 256 slots

  bf16x8 areg[2], breg;
  auto loadT = [&](int k0) {
    areg[0] = *(const bf16x8*)(A + (long)(m0 + ar0) * 1024 + k0 + ac0 * 8);
    areg[1] = *(const bf16x8*)(A + (long)(m0 + ar1) * 1024 + k0 + ac1 * 8);
    breg = *(const bf16x8*)(Bt + (long)(n0 + brow) * 1024 + k0 + bc * 8);
  };
  auto writeT = [&]() {
    *(bf16x8*)(As + ar0 * 34 + ac0 * 8) = areg[0];
    *(bf16x8*)(As + ar1 * 34 + ac1 * 8) = areg[1];
    *(bf16x8*)(Bs + brow * 34 + bc * 8) = breg;
  };

  loadT(0);
  writeT();
  __syncthreads();

  f32x4 acc[2][4] = {};
  for (int k0 = 0; k0 < 1024; k0 += 32) {
    const bool pre = (k0 + 32) < 1024;
    if (pre) loadT(k0 + 32);
    bf16x8 af[2], bfr[4];
    #pragma unroll
    for (int mt = 0; mt < 2; ++mt)
      af[mt] = *(const bf16x8*)(As + (wave * 32 + mt * 16 + l16) * 34 + quad * 8);
    #pragma unroll
    for (int nt = 0; nt < 4; ++nt)
      bfr[nt] = *(const bf16x8*)(Bs + (nt * 16 + l16) * 34 + quad * 8);
    #pragma unroll
    for (int mt = 0; mt < 2; ++mt)
      #pragma unroll
      for (int nt = 0; nt < 4; ++nt)
        acc[mt][nt] = __builtin_amdgcn_mfma_f32_16x16x32_bf16(af[mt], bfr[nt], acc[mt][nt], 0, 0, 0);
    __syncthreads();
    if (pre) writeT();
    __syncthreads();
  }
  #pragma unroll
  for (int mt = 0; mt < 2; ++mt)
    #pragma unroll
    for (int nt = 0; nt < 4; ++nt) {
      int col = n0 + nt * 16 + l16;
      #pragma unroll
      for (int r = 0; r < 4; ++r) {
        int row = m0 + wave * 32 + mt * 16 + quad * 4 + r;
        C[(long)row * 1024 + col] = acc[mt][nt][r] + bias[col];
      }
    }
}

// ---------------- flash attention v5 -------------------------------------
// 512 threads, q-tile 128 (16 rows/wave), grid 512 = 2 blocks/CU for
// uncorrelated barrier phases. All LDS rows stride 68 u16 (34 dwords, odd)
// -> <=2-way bank aliasing everywhere. K/V reg-prefetch staging.
// bh = blockIdx&31 keeps each head's tiles on one XCD (L2-resident K/V).
__global__ __launch_bounds__(512, 4) void k_flash(const u16* __restrict__ Qp,
                                                  const u16* __restrict__ Kp,
                                                  const u16* __restrict__ Vt,
                                                  u16* __restrict__ ctx) {
  __shared__ __align__(16) u16 qs[128 * 68];  // Q tile; becomes per-wave P space
  __shared__ __align__(16) u16 ks[64 * 68];
  __shared__ __align__(16) u16 vs[64 * 68];
  const int t = threadIdx.x, lane = t & 63, quad = lane >> 4, l16 = lane & 15;
  const int wave = t >> 6;                    // 0..7
  const int bh = blockIdx.x & 31, b = bh >> 4, h = bh & 15;
  const int q0 = (blockIdx.x >> 5) * 128;
  const long gkbase = (long)b * 2097152 + h * 64;
  const long gvbase = (long)bh * 131072;
  const int srow = t >> 3, sc = t & 7;        // K/V staging: 64 rows x 8 chunks

  // ---- startup: Q (128x64, 2 slots/thread) + K/V tile 0, all via regs ----
  const long gq = (long)(b * 2048 + q0) * 1024 + h * 64;
  bf16x8 q0r = *(const bf16x8*)(Qp + gq + (long)(t >> 3) * 1024 + (t & 7) * 8);
  bf16x8 q1r = *(const bf16x8*)(Qp + gq + (long)((t + 512) >> 3) * 1024 + (t & 7) * 8);
  bf16x8 kreg = *(const bf16x8*)(Kp + gkbase + (long)srow * 1024 + sc * 8);
  bf16x8 vreg = *(const bf16x8*)(Vt + gvbase + (long)srow * 2048 + sc * 8);
  *(bf16x8*)(qs + (t >> 3) * 68 + (t & 7) * 8) = q0r;
  *(bf16x8*)(qs + ((t + 512) >> 3) * 68 + (t & 7) * 8) = q1r;
  *(bf16x8*)(ks + srow * 68 + sc * 8) = kreg;
  *(bf16x8*)(vs + srow * 68 + sc * 8) = vreg;
  __syncthreads();

  // Q fragments: wave w owns q-rows w*16..w*16+15 == its future P region,
  // so no barrier is needed before reusing those rows for P (per-wave private,
  // DS ops within a wave are ordered).
  bf16x8 qf[2];
  #pragma unroll
  for (int kh = 0; kh < 2; ++kh)
    qf[kh] = *(const bf16x8*)(qs + (wave * 16 + l16) * 68 + kh * 32 + quad * 8);
  u16* pw = qs + wave * 16 * 68;  // per-wave P tile: 16 q-rows x 64 kv

  float lsum[4] = {};
  f32x4 o[4] = {};

  for (int kt = 0; kt < 32; ++kt) {
    if (kt < 31) {  // prefetch next K/V tile into regs (drains at end barrier)
      int kv0 = (kt + 1) * 64;
      kreg = *(const bf16x8*)(Kp + gkbase + (long)(kv0 + srow) * 1024 + sc * 8);
      vreg = *(const bf16x8*)(Vt + gvbase + kv0 + (long)srow * 2048 + sc * 8);
    }

    // S(16x64) = Q @ K^T ; p = exp2(s) ; P -> LDS row-major [q][kv]
    #pragma unroll
    for (int nt = 0; nt < 4; ++nt) {
      f32x4 a = {};
      #pragma unroll
      for (int kh = 0; kh < 2; ++kh) {
        bf16x8 kf = *(const bf16x8*)(ks + (nt * 16 + l16) * 68 + kh * 32 + quad * 8);
        a = __builtin_amdgcn_mfma_f32_16x16x32_bf16(qf[kh], kf, a, 0, 0, 0);
      }
      #pragma unroll
      for (int r = 0; r < 4; ++r) {
        float e = __builtin_amdgcn_exp2f(a[r]);
        lsum[r] += e;
        pw[(quad * 4 + r) * 68 + nt * 16 + l16] = f2bf(e);
      }
    }

    // O(16x64) += P @ V
    #pragma unroll
    for (int kh = 0; kh < 2; ++kh) {
      bf16x8 pa = *(const bf16x8*)(pw + l16 * 68 + kh * 32 + quad * 8);
      #pragma unroll
      for (int nt = 0; nt < 4; ++nt) {
        bf16x8 vf = *(const bf16x8*)(vs + (nt * 16 + l16) * 68 + kh * 32 + quad * 8);
        o[nt] = __builtin_amdgcn_mfma_f32_16x16x32_bf16(pa, vf, o[nt], 0, 0, 0);
      }
    }

    __syncthreads();  // all waves done reading ks/vs; prefetch drained
    if (kt < 31) {
      *(bf16x8*)(ks + srow * 68 + sc * 8) = kreg;
      *(bf16x8*)(vs + srow * 68 + sc * 8) = vreg;
    }
    __syncthreads();  // next tile visible
  }

  // final l reduction across the 16 kv-lanes, then normalize + write
  #pragma unroll
  for (int r = 0; r < 4; ++r) {
    float l = lsum[r];
    #pragma unroll
    for (int d = 1; d < 16; d <<= 1) l += __shfl_xor(l, d);
    lsum[r] = 1.0f / l;
  }
  #pragma unroll
  for (int nt = 0; nt < 4; ++nt)
    #pragma unroll
    for (int r = 0; r < 4; ++r) {
      int q = q0 + wave * 16 + quad * 4 + r;
      long idx = (long)(b * 2048 + q) * 1024 + h * 64 + nt * 16 + l16;
      ctx[idx] = f2bf(o[nt][r] * lsum[r]);
    }
}

extern "C" void kernel_launch(void* const* d_in, const int* in_sizes, int n_in,
                              void* d_out, int out_size, void* d_ws, size_t ws_size,
                              hipStream_t stream) {
  const float* query = (const float*)d_in[0];
  const float* key   = (const float*)d_in[1];
  const float* value = (const float*)d_in[2];
  const float* Wq    = (const float*)d_in[3];
  const float* Wk    = (const float*)d_in[4];
  const float* Wv    = (const float*)d_in[5];
  const float* out_w = (const float*)d_in[6];
  const float* out_b = (const float*)d_in[7];
  // d_in[8] = coupling: unused — per-head scalar bias is softmax-invariant.
  float* out = (float*)d_out;

  char* ws = (char*)d_ws;
  size_t off = 0;
  auto alloc = [&](size_t bytes) {
    void* p = ws + off;
    off += (bytes + 255) & ~(size_t)255;
    return p;
  };
  // wtq..wtv contiguous (k_transpose_w z-stride); Qp,Kp,Vp contiguous
  // (k_gemm_qkv z-stride).
  u16* wtq = (u16*)alloc(1024L * 1024 * 2);
  u16* wtk = (u16*)alloc(1024L * 1024 * 2);
  u16* wtv = (u16*)alloc(1024L * 1024 * 2);
  u16* wto = (u16*)alloc(1024L * 1024 * 2);
  u16* Qp  = (u16*)alloc(4096L * 1024 * 2);
  u16* Kp  = (u16*)alloc(4096L * 1024 * 2);
  u16* Vp  = (u16*)alloc(4096L * 1024 * 2);
  u16* Vtb = (u16*)alloc(4096L * 1024 * 2);
  u16* ctx = (u16*)alloc(4096L * 1024 * 2);
  (void)wtk; (void)wtv; (void)Kp; (void)Vp;

  // Wq/Wk/Wv -> Bt (NxK) bf16 (fused).  wt[w][h*64+k][d] = W[w][h][d][k]
  k_transpose_w<<<dim3(16, 1, 48), 256, 0, stream>>>(Ptr3{Wq, Wk, Wv}, wtq);
  // out_w (K x N) -> wto (N x K)
  k_transpose_bf16<<<dim3(16, 16, 1), 256, 0, stream>>>(out_w, 1, wto, 1024, 1024, 1, 0L, 0L);

  // fused cast + Q,K,V projections (Q pre-scaled by 0.125*log2(e))
  k_gemm_qkv<<<dim3(8, 32, 3), 256, 0, stream>>>(Ptr3{query, key, value}, wtq, Qp, QSCALE);

  // V -> V^T per (b,h): Vt[bh][dim][l]
  k_transpose_bf16<<<dim3(32, 1, 32), 256, 0, stream>>>(Vp, 0, Vtb, 1024, 2048, 16, 64L, 2097152L);

  // attention: grid 512 = 16 q-tiles x 32 bh, bh in low 5 bits for XCD affinity
  k_flash<<<512, 512, 0, stream>>>(Qp, Kp, Vtb, ctx);

  // output projection + bias -> f32
  k_gemm_out<<<dim3(16, 32), 256, 0, stream>>>(ctx, wto, out, out_b);
}